// Round 1
// baseline (319.586 us; speedup 1.0000x reference)
//
#include <hip/hip_runtime.h>
#include <hip/hip_bf16.h>
#include <math.h>

#define TT   1024
#define HH   1024
#define II   512
#define EE   32
#define NE   40
#define TOPK 4
#define CAP  1024

#define GM  128   // m-tile (slots)
#define GNP 16    // gate/up pairs per column tile -> 32 B-rows (16 gate + 16 up)
#define GK  32    // k-slab
#define KP  40    // LDS pitch (bf16): 80 B, 16B-aligned, 2-way banks (free)
#define DN  32    // down n-tile (32 B-rows)

typedef __attribute__((ext_vector_type(4))) short short4v;
typedef __attribute__((ext_vector_type(8))) short short8v;
typedef __attribute__((ext_vector_type(4))) float floatx4;

static __device__ __forceinline__ short f2bf(float f) {
    unsigned u = __float_as_uint(f);
    unsigned r = (u + 0x7fffu + ((u >> 16) & 1u)) >> 16;
    return (short)(r & 0xffffu);
}
static __device__ __forceinline__ float bf2f(short s) {
    return __uint_as_float(((unsigned)(unsigned short)s) << 16);
}
#if defined(__has_builtin)
#if __has_builtin(__builtin_amdgcn_cvt_pk_bf16_f32)
#define HAVE_PK_BF16 1
#endif
#endif
static __device__ __forceinline__ unsigned pk2(float a, float b) {
#ifdef HAVE_PK_BF16
    typedef __attribute__((ext_vector_type(2))) __bf16 bf2t;
    union { bf2t v; unsigned u; } cv;
    cv.v = __builtin_amdgcn_cvt_pk_bf16_f32(a, b);
    return cv.u;
#else
    return (unsigned)(unsigned short)f2bf(a) | ((unsigned)(unsigned short)f2bf(b) << 16);
#endif
}
static __device__ __forceinline__ short4v cvt4(float4 v) {
    union { unsigned u[2]; short4v s; } cv;
    cv.u[0] = pk2(v.x, v.y); cv.u[1] = pk2(v.z, v.w);
    return cv.s;
}

// shared-memory block: 10240 + 2560 + 512 + 512 = 13824 B
struct SMem {
    short As[GM * KP];        // 128 rows
    short Bs[2 * GNP * KP];   // 32 rows (gate 0..15, up 16..31 / down cols)
    int   sl[GM];
    float wvs[GM];
};

// ---------------- workspace layout (bytes) ----------------
// counts @0, topk_w @1024, zero_w @17408, kexp @21504, slots @40960,
// xb @262144 (2MB), hmid @2359296 (4MB), ydown @6553600 (8MB)

// ================= Phase A: router (waves 0,1) + xconv (waves 2,3) ============
__global__ __launch_bounds__(256, 4) void kA(
    const float* __restrict__ x, const float* __restrict__ rw,
    const float* __restrict__ bias, float* __restrict__ topk_w,
    float* __restrict__ zero_w, int* __restrict__ kexp,
    int* __restrict__ counts, int* __restrict__ slots, short* __restrict__ xb)
{
    const int bx = blockIdx.x, tid = threadIdx.x;
    const int lane = tid & 63;
    const int w    = tid >> 6;

    if (w < 2) {
        const int t = bx * 2 + w;
        float xv[16];
        #pragma unroll
        for (int i = 0; i < 16; ++i) xv[i] = x[(size_t)t * HH + 64 * i + lane];

        float mylogit = -INFINITY;
        for (int e0 = 0; e0 < NE; e0 += 4) {
            const float* r0 = rw + (size_t)e0 * HH;
            float p[4] = { 0.f, 0.f, 0.f, 0.f };
            #pragma unroll
            for (int i = 0; i < 16; ++i) {
                int h = 64 * i + lane;
                #pragma unroll
                for (int j = 0; j < 4; ++j) p[j] += xv[i] * r0[(size_t)j * HH + h];
            }
            #pragma unroll
            for (int j = 0; j < 4; ++j) {
                #pragma unroll
                for (int off = 32; off > 0; off >>= 1) p[j] += __shfl_xor(p[j], off);
                if (lane == e0 + j) mylogit = p[j];
            }
        }

        float m = mylogit;
        #pragma unroll
        for (int off = 32; off > 0; off >>= 1) m = fmaxf(m, __shfl_xor(m, off));
        float pexp = (lane < NE) ? expf(mylogit - m) : 0.f;
        float s = pexp;
        #pragma unroll
        for (int off = 32; off > 0; off >>= 1) s += __shfl_xor(s, off);
        const float score = pexp / s;

        float val = (lane < NE) ? score + bias[lane] : -INFINITY;
        int   kidx[TOPK];
        float kw[TOPK];
        #pragma unroll
        for (int k = 0; k < TOPK; ++k) {
            float v = val; int idx = lane;
            #pragma unroll
            for (int off = 32; off > 0; off >>= 1) {
                float ov = __shfl_xor(v, off);
                int   oi = __shfl_xor(idx, off);
                if (ov > v || (ov == v && oi < idx)) { v = ov; idx = oi; }
            }
            kidx[k] = idx;
            kw[k]   = __shfl(score, idx);
            if (lane == idx) val = -INFINITY;
        }

        if (lane == 0) {
            float zw = 0.f;
            #pragma unroll
            for (int k = 0; k < TOPK; ++k) {
                int slot = t * TOPK + k;
                topk_w[slot] = kw[k];
                kexp[slot]   = kidx[k];
                if (kidx[k] < EE) {
                    int pos = atomicAdd(&counts[kidx[k]], 1);
                    slots[kidx[k] * CAP + pos] = slot;
                } else {
                    zw += kw[k];
                }
            }
            zero_w[t] = zw;
        }
    } else {
        const int t = bx * 2 + (w - 2);
        const float4* xr = (const float4*)(x + (size_t)t * HH);
        short4v* xbr = (short4v*)(xb + (size_t)t * HH);
        #pragma unroll
        for (int i = 0; i < 4; ++i) xbr[lane + 64 * i] = cvt4(xr[lane + 64 * i]);
    }
}

// ================= Phase B: gate_up bf16 MFMA + SiLU ==========================
// grid 1024 = E(32) x 32 column tiles; 4 waves each own a 32-row m-quarter.
__global__ __launch_bounds__(256, 4) void kB(
    const short* __restrict__ xb, const float* __restrict__ wgu,
    const int* __restrict__ counts, const int* __restrict__ slots,
    const float* __restrict__ topk_w, short* __restrict__ hmid)
{
    __shared__ SMem sm;
    const int bx = blockIdx.x, tid = threadIdx.x;
    const int e      = bx >> 5;
    const int c_base = (bx & 31) * GNP;
    const int cnt    = counts[e];
    const float* wb  = wgu + (size_t)e * (2 * II) * HH;

    const int lane = tid & 63;
    const int w    = tid >> 6;        // 0..3: m-quarter
    const int quad = lane >> 4;
    const int mcol = lane & 15;

    for (int m_base = 0; m_base < cnt; m_base += GM) {
        if (tid < GM) {
            int m = m_base + tid;
            int s = (m < cnt) ? slots[e * CAP + m] : -1;
            sm.sl[tid]  = s;
            sm.wvs[tid] = (s >= 0) ? topk_w[s] : 0.f;
        }
        __syncthreads();

        const int kcA = tid & 3;
        int rowA[2]; int slA[2]; const short* pA[2];
        #pragma unroll
        for (int it = 0; it < 2; ++it) {
            rowA[it] = (tid >> 2) + 64 * it;
            int s = sm.sl[rowA[it]];
            slA[it] = s;
            pA[it] = xb + (size_t)((s >= 0 ? s : 0) >> 2) * HH + kcA * 8;
        }
        const int kq   = tid & 7;
        const int rowB = tid >> 3;    // 0..31
        const int grow = (rowB < GNP) ? (c_base + rowB)
                                      : (II + c_base + (rowB - GNP));
        const float* pB = wb + (size_t)grow * HH + kq * 4;

        floatx4 accg[2] = {};
        floatx4 accu[2] = {};
        short8v pa[2]; float4 pb;
        const short8v szv = { 0,0,0,0,0,0,0,0 };

        // prefetch slab 0 into registers
        #pragma unroll
        for (int it = 0; it < 2; ++it) pa[it] = (slA[it] >= 0) ? *(const short8v*)(pA[it]) : szv;
        pb = *(const float4*)(pB);

        for (int k0 = 0; k0 < HH; k0 += GK) {
            #pragma unroll
            for (int it = 0; it < 2; ++it) *(short8v*)&sm.As[rowA[it] * KP + kcA * 8] = pa[it];
            *(short4v*)&sm.Bs[rowB * KP + kq * 4] = cvt4(pb);
            __syncthreads();

            const int kn = k0 + GK;
            if (kn < HH) {   // issue next-slab loads; in flight during MFMA
                #pragma unroll
                for (int it = 0; it < 2; ++it) pa[it] = (slA[it] >= 0) ? *(const short8v*)(pA[it] + kn) : szv;
                pb = *(const float4*)(pB + kn);
            }

            short8v a[2], bg, bu;
            #pragma unroll
            for (int i = 0; i < 2; ++i)
                a[i] = *(const short8v*)&sm.As[(w * 32 + i * 16 + mcol) * KP + quad * 8];
            bg = *(const short8v*)&sm.Bs[(mcol) * KP + quad * 8];
            bu = *(const short8v*)&sm.Bs[(GNP + mcol) * KP + quad * 8];
            #pragma unroll
            for (int i = 0; i < 2; ++i) {
                accg[i] = __builtin_amdgcn_mfma_f32_16x16x32_bf16(a[i], bg, accg[i], 0, 0, 0);
                accu[i] = __builtin_amdgcn_mfma_f32_16x16x32_bf16(a[i], bu, accu[i], 0, 0, 0);
            }
            __syncthreads();
        }

        #pragma unroll
        for (int i = 0; i < 2; ++i) {
            #pragma unroll
            for (int r = 0; r < 4; ++r) {
                int m = w * 32 + i * 16 + quad * 4 + r;
                int s = sm.sl[m];
                if (s < 0) continue;
                float g = accg[i][r], u = accu[i][r];
                float valf = sm.wvs[m] * g * u / (1.f + __expf(-g));
                hmid[(size_t)s * II + c_base + mcol] = f2bf(valf);
            }
        }
        __syncthreads();
    }
}

// ================= Phase C: down bf16 MFMA -> ydown ===========================
// grid 1024 = E(32) x 32 n-tiles of 32 cols.
__global__ __launch_bounds__(256, 4) void kC(
    const short* __restrict__ hmid, const float* __restrict__ wd,
    const int* __restrict__ counts, const int* __restrict__ slots,
    short* __restrict__ ydown)
{
    __shared__ SMem sm;
    const int bx = blockIdx.x, tid = threadIdx.x;
    const int e      = bx >> 5;
    const int n_base = (bx & 31) * DN;
    const int cnt    = counts[e];
    const float* wb  = wd + (size_t)e * HH * II;

    const int lane = tid & 63;
    const int w    = tid >> 6;        // 0..3: m-quarter
    const int quad = lane >> 4;
    const int mcol = lane & 15;

    for (int m_base = 0; m_base < cnt; m_base += GM) {
        if (tid < GM) {
            int m = m_base + tid;
            sm.sl[tid] = (m < cnt) ? slots[e * CAP + m] : -1;
        }
        __syncthreads();

        const int kcA = tid & 3;
        int rowA[2]; int slA[2]; const short* pA[2];
        #pragma unroll
        for (int it = 0; it < 2; ++it) {
            rowA[it] = (tid >> 2) + 64 * it;
            int s = sm.sl[rowA[it]];
            slA[it] = s;
            pA[it] = hmid + (size_t)(s >= 0 ? s : 0) * II + kcA * 8;
        }
        const int kq   = tid & 7;
        const int rowB = tid >> 3;    // 0..31
        const float* pB = wb + (size_t)(n_base + rowB) * II + kq * 4;

        floatx4 acc[2][2] = {};
        short8v pa[2]; float4 pb;
        const short8v szv = { 0,0,0,0,0,0,0,0 };

        #pragma unroll
        for (int it = 0; it < 2; ++it) pa[it] = (slA[it] >= 0) ? *(const short8v*)(pA[it]) : szv;
        pb = *(const float4*)(pB);

        for (int k0 = 0; k0 < II; k0 += GK) {
            #pragma unroll
            for (int it = 0; it < 2; ++it) *(short8v*)&sm.As[rowA[it] * KP + kcA * 8] = pa[it];
            *(short4v*)&sm.Bs[rowB * KP + kq * 4] = cvt4(pb);
            __syncthreads();

            const int kn = k0 + GK;
            if (kn < II) {
                #pragma unroll
                for (int it = 0; it < 2; ++it) pa[it] = (slA[it] >= 0) ? *(const short8v*)(pA[it] + kn) : szv;
                pb = *(const float4*)(pB + kn);
            }

            short8v a[2], b[2];
            #pragma unroll
            for (int i = 0; i < 2; ++i)
                a[i] = *(const short8v*)&sm.As[(w * 32 + i * 16 + mcol) * KP + quad * 8];
            #pragma unroll
            for (int j = 0; j < 2; ++j)
                b[j] = *(const short8v*)&sm.Bs[(j * 16 + mcol) * KP + quad * 8];
            #pragma unroll
            for (int i = 0; i < 2; ++i)
                #pragma unroll
                for (int j = 0; j < 2; ++j)
                    acc[i][j] = __builtin_amdgcn_mfma_f32_16x16x32_bf16(a[i], b[j], acc[i][j], 0, 0, 0);
            __syncthreads();
        }

        #pragma unroll
        for (int i = 0; i < 2; ++i) {
            #pragma unroll
            for (int r = 0; r < 4; ++r) {
                int m = w * 32 + i * 16 + quad * 4 + r;
                int s = sm.sl[m];
                if (s < 0) continue;
                short* yrow = ydown + (size_t)s * HH + n_base;
                #pragma unroll
                for (int j = 0; j < 2; ++j)
                    yrow[j * 16 + mcol] = f2bf(acc[i][j][r]);
            }
        }
        __syncthreads();
    }
}

// ================= Phase D: combine (grid 1024, 1 token/block) ================
__global__ __launch_bounds__(256, 4) void kD(
    const float* __restrict__ x, const short* __restrict__ ydown,
    const int* __restrict__ kexp, const float* __restrict__ zero_w,
    float* __restrict__ out)
{
    const int bx = blockIdx.x, tid = threadIdx.x;
    const int t = bx;
    const float4 xvv = ((const float4*)(x + (size_t)t * HH))[tid];
    const float zw = zero_w[t];
    float4 o;
    o.x = zw * xvv.x; o.y = zw * xvv.y; o.z = zw * xvv.z; o.w = zw * xvv.w;
    #pragma unroll
    for (int k = 0; k < TOPK; ++k) {
        int slot = t * TOPK + k;
        if (kexp[slot] < EE) {
            short4v y = *(const short4v*)&ydown[(size_t)slot * HH + tid * 4];
            o.x += bf2f(y[0]); o.y += bf2f(y[1]);
            o.z += bf2f(y[2]); o.w += bf2f(y[3]);
        }
    }
    ((float4*)(out + (size_t)t * HH))[tid] = o;
}

extern "C" void kernel_launch(void* const* d_in, const int* in_sizes, int n_in,
                              void* d_out, int out_size, void* d_ws, size_t ws_size,
                              hipStream_t stream) {
    const float* x    = (const float*)d_in[0];
    const float* rw   = (const float*)d_in[1];
    const float* bias = (const float*)d_in[2];
    const float* wgu  = (const float*)d_in[3];
    const float* wd   = (const float*)d_in[4];
    float* out = (float*)d_out;

    char* ws = (char*)d_ws;
    int*   counts = (int*)ws;
    float* topk_w = (float*)(ws + 1024);
    float* zero_w = (float*)(ws + 17408);
    int*   kexp   = (int*)(ws + 21504);
    int*   slots  = (int*)(ws + 40960);
    short* xb     = (short*)(ws + 262144);
    short* hmid   = (short*)(ws + 2359296);
    short* ydown  = (short*)(ws + 6553600);

    hipMemsetAsync(counts, 0, EE * sizeof(int), stream);

    kA<<<dim3(512),  dim3(256), 0, stream>>>(x, rw, bias, topk_w, zero_w, kexp, counts, slots, xb);
    kB<<<dim3(1024), dim3(256), 0, stream>>>(xb, wgu, counts, slots, topk_w, hmid);
    kC<<<dim3(1024), dim3(256), 0, stream>>>(hmid, wd, counts, slots, ydown);
    kD<<<dim3(1024), dim3(256), 0, stream>>>(x, ydown, kexp, zero_w, out);
}